// Round 1
// baseline (182.303 us; speedup 1.0000x reference)
//
#include <hip/hip_runtime.h>

// SoftNCutsLoss fused kernel for MI355X.
// Key algebra: dist weight depends only on dz (last axis), mask keeps dz in {-1,0,1}.
// w(b,p,off) = exp(-(I[p+off]-I[p])^2/100) * wz(dz),  wz(0)=1, wz(+-1)=exp(-3/16).
// num_s[k,p] = sum_b sum_off w * preds_pad[b,k,p+off];  den_s[p] = sum_b sum_off w.
// numerator[b,k] = sum_p preds[b,k,p]*num_s[k,p]; denominator[b,k] = sum_p preds[b,k,p]*den_s[p]
// out[b] = K - sum_k (num+eps)/(den+eps)

constexpr int Pdim = 64;
constexpr int P3   = Pdim * Pdim * Pdim;   // 262144
constexpr int Rxy  = 4;
constexpr int TX = 8, TY = 8, TZ = 8;
constexpr int ZLEN = 2;                     // voxels per thread along z
constexpr int RGX = TX + 2 * Rxy;           // 16
constexpr int RGY = TY + 2 * Rxy;           // 16
constexpr int RGZ = TZ + 2;                 // 10 (dz halo is +-1)
constexpr int YP  = 17;                     // padded y pitch (bank conflicts)
constexpr int ZP  = 11;                     // padded z pitch (bank conflicts)
constexpr int NREP = 16;                    // replicated atomic accumulators

#define EPSF 2.2204460492503131e-16f

__global__ __launch_bounds__(256, 2)
void ncuts_main(const float* __restrict__ batch, const float* __restrict__ preds,
                float* __restrict__ acc) {
  __shared__ float  sB[RGX][YP][ZP];   // batch halo tile (one b at a time)
  __shared__ float4 sP[RGX][YP][ZP];   // preds halo tile, k packed in float4
  __shared__ float  red[4][32];        // cross-wave reduction scratch

  const int t   = threadIdx.x;
  const int tx  = t & 7;
  const int ty  = (t >> 3) & 7;
  const int tzt = t >> 6;              // 0..3, one z-column of ZLEN voxels each
  const int bx0 = blockIdx.x * TX, by0 = blockIdx.y * TY, bz0 = blockIdx.z * TZ;
  const int x = bx0 + tx, y = by0 + ty, z0 = bz0 + tzt * ZLEN;
  const int zc = tzt * ZLEN;           // region-z of the dz=-1 neighbor of voxel j=0

  float  den[ZLEN];
  float4 num[ZLEN];
#pragma unroll
  for (int j = 0; j < ZLEN; ++j) { den[j] = 0.f; num[j] = make_float4(0.f, 0.f, 0.f, 0.f); }

  // w_int * wz = 2^(d*d*C1 + LWZ), fused exponent
  const float C1   = -0.014426950408889634f;   // -log2(e)/SIGMA_I^2 = -log2(e)/100
  const float LWZ1 = -0.27050531991668065f;    // log2(exp(-3/16))

  for (int b = 0; b < 4; ++b) {
    __syncthreads();   // protect previous iteration's LDS reads
    // ---- stage halo region for this b ----
    for (int idx = t; idx < RGX * RGY * RGZ; idx += 256) {
      int rz = idx % RGZ;
      int rq = idx / RGZ;
      int ry = rq % RGY;
      int rx = rq / RGY;
      int gx = bx0 + rx - Rxy, gy = by0 + ry - Rxy, gz = bz0 + rz - 1;
      bool in = ((unsigned)gx < (unsigned)Pdim) & ((unsigned)gy < (unsigned)Pdim) &
                ((unsigned)gz < (unsigned)Pdim);
      float  v  = EPSF;
      float4 pv = make_float4(EPSF, EPSF, EPSF, EPSF);
      if (in) {
        int gi = (gx * Pdim + gy) * Pdim + gz;
        v = batch[b * P3 + gi];
        const float* pp = preds + b * 4 * P3 + gi;
        pv.x = pp[0]; pv.y = pp[P3]; pv.z = pp[2 * P3]; pv.w = pp[3 * P3];
      }
      sB[rx][ry][rz] = v;
      sP[rx][ry][rz] = pv;
    }
    __syncthreads();

    float I0[ZLEN];
#pragma unroll
    for (int j = 0; j < ZLEN; ++j) I0[j] = sB[tx + Rxy][ty + Rxy][zc + 1 + j];

#pragma unroll 1
    for (int dy = 0; dy < 9; ++dy) {
#pragma unroll 3
      for (int dx = 0; dx < 9; ++dx) {
        const float*  cb = &sB[tx + dx][ty + dy][zc];
        const float4* cp = &sP[tx + dx][ty + dy][zc];
        float  colB[ZLEN + 2];
        float4 colP[ZLEN + 2];
#pragma unroll
        for (int j = 0; j < ZLEN + 2; ++j) { colB[j] = cb[j]; colP[j] = cp[j]; }
#pragma unroll
        for (int j = 0; j < ZLEN; ++j) {
#pragma unroll
          for (int dz = 0; dz < 3; ++dz) {   // dz index: 0,1,2 -> actual -1,0,+1
            float d   = colB[j + dz] - I0[j];
            float arg = __builtin_fmaf(d * d, C1, (dz == 1) ? 0.f : LWZ1);
            float w   = exp2f(arg);
            den[j] += w;
            float4 p = colP[j + dz];
            num[j].x = __builtin_fmaf(w, p.x, num[j].x);
            num[j].y = __builtin_fmaf(w, p.y, num[j].y);
            num[j].z = __builtin_fmaf(w, p.z, num[j].z);
            num[j].w = __builtin_fmaf(w, p.w, num[j].w);
          }
        }
      }
    }
  }

  // ---- phase 2: fused einsums -> per-thread partial num/den per (b,k) ----
  float pn[16], pd[16];
#pragma unroll
  for (int i = 0; i < 16; ++i) { pn[i] = 0.f; pd[i] = 0.f; }
#pragma unroll
  for (int b = 0; b < 4; ++b) {
#pragma unroll
    for (int j = 0; j < ZLEN; ++j) {
      const float* pp = preds + b * 4 * P3 + ((x * Pdim + y) * Pdim + z0 + j);
      float ns[4] = {num[j].x, num[j].y, num[j].z, num[j].w};
#pragma unroll
      for (int k = 0; k < 4; ++k) {
        float pv = pp[k * P3];
        pn[b * 4 + k] = __builtin_fmaf(pv, ns[k],  pn[b * 4 + k]);
        pd[b * 4 + k] = __builtin_fmaf(pv, den[j], pd[b * 4 + k]);
      }
    }
  }

  // ---- reduce 32 values across the block ----
#pragma unroll
  for (int i = 0; i < 16; ++i) {
#pragma unroll
    for (int off = 32; off > 0; off >>= 1) {
      pn[i] += __shfl_down(pn[i], off, 64);
      pd[i] += __shfl_down(pd[i], off, 64);
    }
  }
  const int wave = t >> 6, lane = t & 63;
  if (lane == 0) {
#pragma unroll
    for (int i = 0; i < 16; ++i) { red[wave][i] = pn[i]; red[wave][16 + i] = pd[i]; }
  }
  __syncthreads();
  if (t < 32) {
    float s = red[0][t] + red[1][t] + red[2][t] + red[3][t];
    int bid = blockIdx.x + 8 * (blockIdx.y + 8 * (int)blockIdx.z);
    atomicAdd(&acc[(bid & (NREP - 1)) * 32 + t], s);
  }
}

__global__ void ncuts_zero(float* __restrict__ acc) {
  int t = threadIdx.x;
  if (t < NREP * 32) acc[t] = 0.f;
}

__global__ void ncuts_final(const float* __restrict__ acc, float* __restrict__ out) {
  __shared__ float loss[16];
  int t = threadIdx.x;
  if (t < 16) {
    float n = 0.f, d = 0.f;
    for (int r = 0; r < NREP; ++r) { n += acc[r * 32 + t]; d += acc[r * 32 + 16 + t]; }
    loss[t] = (n + EPSF) / (d + EPSF);
  }
  __syncthreads();
  if (t < 4) {
    float s = loss[t * 4] + loss[t * 4 + 1] + loss[t * 4 + 2] + loss[t * 4 + 3];
    out[t] = 4.0f - s;
  }
}

extern "C" void kernel_launch(void* const* d_in, const int* in_sizes, int n_in,
                              void* d_out, int out_size, void* d_ws, size_t ws_size,
                              hipStream_t stream) {
  const float* batch = (const float*)d_in[0];
  const float* preds = (const float*)d_in[1];
  float* out = (float*)d_out;
  float* acc = (float*)d_ws;   // NREP*32 floats = 2 KB

  hipLaunchKernelGGL(ncuts_zero, dim3(1), dim3(512), 0, stream, acc);
  hipLaunchKernelGGL(ncuts_main, dim3(8, 8, 8), dim3(256), 0, stream, batch, preds, acc);
  hipLaunchKernelGGL(ncuts_final, dim3(1), dim3(64), 0, stream, acc, out);
}

// Round 2
// 111.617 us; speedup vs baseline: 1.6333x; 1.6333x over previous
//
#include <hip/hip_runtime.h>

// SoftNCutsLoss via rank-2 separable factorization of the bilateral weight.
// w = exp(-(Iw-I0)^2/100)*wz(dz) ; exp(Iw*I0/50) ~= 1 + Iw*I0/50 (rel err <= 2e-4)
//  => w ~= [g(I0)]*[g(Iw)]*wz + [g(I0)*I0/50]*[g(Iw)*Iw]*wz,  g(u)=exp(-u^2/100)
// num_map[b',k] = sum_m a_m(I0) * Box( f_m * pred[b',k] ),  Box = 1_9x9 (x) [wz,1,wz]
// den_map[b']  = sum_m a_m(I0) * Box( f_m ) + g(I0)*(Wfull - inbounds(p))   (EPS pad)
// Box is separable: passX (x), passY (y), 3-tap z fused into the contraction.

constexpr int Pdim = 64;
constexpr int P3   = Pdim * Pdim * Pdim;   // 262144
constexpr int NREP = 16;

#define EPSF 2.2204460492503131e-16f

constexpr float WZ1   = 0.8290291181804004f;     // exp(-3/16)
constexpr float K2F   = 0.014426950408889634f;   // log2(e)/100
constexpr float C1F   = 0.02f;                   // 1/50
constexpr float WFULL = 81.0f * (1.0f + 2.0f * WZ1);

// ---------------------------------------------------------------------------
// Pass X: U0 = BoxX(g*p), U1 = BoxX(g*I*p)   (p = pred channel or 1 for den)
// thread = one x-line at fixed (y,z); lanes contiguous in z (coalesced).
// ---------------------------------------------------------------------------
template<int X0, int NX, int FIRSTW>
__device__ __forceinline__ void passx_body(const float* __restrict__ Ip,
                                           const float* __restrict__ Pp,
                                           float* __restrict__ U0,
                                           float* __restrict__ U1,
                                           bool isden) {
  float w0[9], w1[9];
#pragma unroll
  for (int i = 0; i < 9; ++i) { w0[i] = 0.f; w1[i] = 0.f; }
  float s0 = 0.f, s1 = 0.f;
#pragma unroll
  for (int i = 0; i < NX; ++i) {
    const int x = X0 + i;
    float u0 = 0.f, u1 = 0.f;
    if (x < 64) {                       // zero-pad outside (pred pad ~ EPS ~ 0)
      float I = Ip[x << 12];
      float g = exp2f(-I * I * K2F);
      float p = isden ? 1.f : Pp[x << 12];
      u0 = g * p;
      u1 = u0 * I;
    }
    const int r = i % 9;                // static after full unroll
    s0 += u0 - w0[r]; w0[r] = u0;
    s1 += u1 - w1[r]; w1[r] = u1;
    if (i >= FIRSTW) {                  // window warm-up guard (seg2 overlap)
      U0[(x - 4) << 12] = s0;
      U1[(x - 4) << 12] = s1;
    }
  }
}

__global__ __launch_bounds__(256)
void ncuts_passx(const float* __restrict__ batch, const float* __restrict__ preds,
                 float* __restrict__ U, float* __restrict__ acc) {
  const int t = threadIdx.x;
  if (blockIdx.x == 0 && blockIdx.y == 0 && blockIdx.z == 0) {
    acc[t] = 0.f; acc[t + 256] = 0.f;   // zero NREP*32 = 512 accumulators
  }
  const int z  = t & 63, ys = t >> 6;
  const int y  = blockIdx.x * 4 + ys;
  const int pair = blockIdx.y;          // b*5 + c, c=0..3 pred channel, c=4 den
  const int b = pair / 5, c = pair - 5 * b;
  const bool isden = (c == 4);
  const int lin = (y << 6) + z;
  const float* Ip = batch + b * P3 + lin;
  const float* Pp = isden ? Ip : preds + (b * 4 + c) * P3 + lin;
  float* U0 = U + (pair * 2 + 0) * P3 + lin;
  float* U1 = U + (pair * 2 + 1) * P3 + lin;
  if (blockIdx.z == 0) passx_body< 0, 36, 4>(Ip, Pp, U0, U1, isden);  // out x 0..31
  else                 passx_body<28, 40, 8>(Ip, Pp, U0, U1, isden);  // out x 32..63
}

// ---------------------------------------------------------------------------
// Pass Y: in-place 9-wide box along y (safe: window held in registers).
// ---------------------------------------------------------------------------
__global__ __launch_bounds__(256)
void ncuts_passy(float* __restrict__ U) {
  const int t = threadIdx.x;
  const int z = t & 63, xs = t >> 6;
  const int x = blockIdx.x * 4 + xs;
  const int fi = blockIdx.y;            // 0..39
  float* base = U + fi * P3 + (x << 12) + z;
  float w[9];
#pragma unroll
  for (int i = 0; i < 9; ++i) w[i] = 0.f;
  float s = 0.f;
#pragma unroll
  for (int y = 0; y < 68; ++y) {
    float u = (y < 64) ? base[y << 6] : 0.f;
    const int r = y % 9;
    s += u - w[r]; w[r] = u;
    if (y >= 4) base[(y - 4) << 6] = s;
  }
}

// ---------------------------------------------------------------------------
// Contract: 3-tap z-comb, rank-2 recombination, fused einsums, block reduce.
// ---------------------------------------------------------------------------
__global__ __launch_bounds__(256)
void ncuts_contract(const float* __restrict__ batch, const float* __restrict__ preds,
                    const float* __restrict__ U, float* __restrict__ acc) {
  __shared__ float red[4][32];
  const int t = threadIdx.x;
  float pn[16], pd[16];
#pragma unroll
  for (int i = 0; i < 16; ++i) { pn[i] = 0.f; pd[i] = 0.f; }

#pragma unroll 1
  for (int it = 0; it < 2; ++it) {
    const int v = blockIdx.x * 512 + it * 256 + t;
    const int z = v & 63, y = (v >> 6) & 63, x = v >> 12;

    float a0[4], a1[4], gsum = 0.f;
#pragma unroll
    for (int b = 0; b < 4; ++b) {
      float I = batch[b * P3 + v];
      float g = exp2f(-I * I * K2F);
      a0[b] = g; a1[b] = g * I * C1F; gsum += g;
    }

    const bool zm = (z > 0), zp = (z < 63);
    float ns[4] = {0.f, 0.f, 0.f, 0.f};
    float ds = 0.f;
#pragma unroll
    for (int b = 0; b < 4; ++b) {
#pragma unroll
      for (int c = 0; c < 5; ++c) {
        const float* up = U + ((b * 5 + c) * 2) * P3 + v;
#pragma unroll
        for (int m = 0; m < 2; ++m) {
          const float* u = up + m * P3;
          float um = u[-1]; um = zm ? um : 0.f;   // guard words exist around U
          float uc = u[0];
          float uq = u[1];  uq = zp ? uq : 0.f;
          float Zc = __builtin_fmaf(WZ1, um + uq, uc);
          float a = m ? a1[b] : a0[b];
          if (c < 4) ns[c] = __builtin_fmaf(a, Zc, ns[c]);
          else       ds    = __builtin_fmaf(a, Zc, ds);
        }
      }
    }
    // den boundary correction: out-of-bounds image cells have w ~= g(I0)*wz(dz)
    float cx = (float)(9 - max(0, 4 - x) - max(0, x - 59));
    float cy = (float)(9 - max(0, 4 - y) - max(0, y - 59));
    float cz = 1.f + WZ1 * (float)((int)zm + (int)zp);
    ds = __builtin_fmaf(gsum, WFULL - cx * cy * cz, ds);

#pragma unroll
    for (int b = 0; b < 4; ++b) {
#pragma unroll
      for (int k = 0; k < 4; ++k) {
        float p = preds[(b * 4 + k) * P3 + v];
        pn[b * 4 + k] = __builtin_fmaf(p, ns[k], pn[b * 4 + k]);
        pd[b * 4 + k] = __builtin_fmaf(p, ds,    pd[b * 4 + k]);
      }
    }
  }

#pragma unroll
  for (int i = 0; i < 16; ++i) {
#pragma unroll
    for (int off = 32; off > 0; off >>= 1) {
      pn[i] += __shfl_down(pn[i], off, 64);
      pd[i] += __shfl_down(pd[i], off, 64);
    }
  }
  const int wave = t >> 6, lane = t & 63;
  if (lane == 0) {
#pragma unroll
    for (int i = 0; i < 16; ++i) { red[wave][i] = pn[i]; red[wave][16 + i] = pd[i]; }
  }
  __syncthreads();
  if (t < 32) {
    float s = red[0][t] + red[1][t] + red[2][t] + red[3][t];
    atomicAdd(&acc[(blockIdx.x & (NREP - 1)) * 32 + t], s);
  }
}

__global__ void ncuts_final(const float* __restrict__ acc, float* __restrict__ out) {
  __shared__ float loss[16];
  int t = threadIdx.x;
  if (t < 16) {
    float n = 0.f, d = 0.f;
    for (int r = 0; r < NREP; ++r) { n += acc[r * 32 + t]; d += acc[r * 32 + 16 + t]; }
    loss[t] = (n + EPSF) / (d + EPSF);
  }
  __syncthreads();
  if (t < 4) {
    float s = loss[t * 4] + loss[t * 4 + 1] + loss[t * 4 + 2] + loss[t * 4 + 3];
    out[t] = 4.0f - s;
  }
}

// ===========================================================================
// Fallback (round-1 direct kernel) if the workspace is too small for U.
// ===========================================================================
constexpr int Rxy = 4;
constexpr int TX = 8, TY = 8;
constexpr int ZLEN = 2;
constexpr int RGX = 16, RGY = 16, RGZ = 10;
constexpr int YP = 17, ZP = 11;

__global__ __launch_bounds__(256, 2)
void ncuts_main(const float* __restrict__ batch, const float* __restrict__ preds,
                float* __restrict__ acc) {
  __shared__ float  sB[RGX][YP][ZP];
  __shared__ float4 sP[RGX][YP][ZP];
  __shared__ float  red[4][32];

  const int t = threadIdx.x;
  const int tx = t & 7, ty = (t >> 3) & 7, tzt = t >> 6;
  const int bx0 = blockIdx.x * TX, by0 = blockIdx.y * TY, bz0 = blockIdx.z * 8;
  const int x = bx0 + tx, y = by0 + ty, z0 = bz0 + tzt * ZLEN;
  const int zc = tzt * ZLEN;

  float  den[ZLEN];
  float4 num[ZLEN];
#pragma unroll
  for (int j = 0; j < ZLEN; ++j) { den[j] = 0.f; num[j] = make_float4(0.f, 0.f, 0.f, 0.f); }

  const float C1 = -0.014426950408889634f;
  const float LWZ1 = -0.27050531991668065f;

  for (int b = 0; b < 4; ++b) {
    __syncthreads();
    for (int idx = t; idx < RGX * RGY * RGZ; idx += 256) {
      int rz = idx % RGZ, rq = idx / RGZ, ry = rq % RGY, rx = rq / RGY;
      int gx = bx0 + rx - Rxy, gy = by0 + ry - Rxy, gz = bz0 + rz - 1;
      bool in = ((unsigned)gx < 64u) & ((unsigned)gy < 64u) & ((unsigned)gz < 64u);
      float v = EPSF; float4 pv = make_float4(EPSF, EPSF, EPSF, EPSF);
      if (in) {
        int gi = (gx * Pdim + gy) * Pdim + gz;
        v = batch[b * P3 + gi];
        const float* pp = preds + b * 4 * P3 + gi;
        pv.x = pp[0]; pv.y = pp[P3]; pv.z = pp[2 * P3]; pv.w = pp[3 * P3];
      }
      sB[rx][ry][rz] = v; sP[rx][ry][rz] = pv;
    }
    __syncthreads();

    float I0[ZLEN];
#pragma unroll
    for (int j = 0; j < ZLEN; ++j) I0[j] = sB[tx + Rxy][ty + Rxy][zc + 1 + j];

#pragma unroll 1
    for (int dy = 0; dy < 9; ++dy) {
#pragma unroll 3
      for (int dx = 0; dx < 9; ++dx) {
        const float*  cb = &sB[tx + dx][ty + dy][zc];
        const float4* cp = &sP[tx + dx][ty + dy][zc];
        float colB[ZLEN + 2]; float4 colP[ZLEN + 2];
#pragma unroll
        for (int j = 0; j < ZLEN + 2; ++j) { colB[j] = cb[j]; colP[j] = cp[j]; }
#pragma unroll
        for (int j = 0; j < ZLEN; ++j) {
#pragma unroll
          for (int dz = 0; dz < 3; ++dz) {
            float d = colB[j + dz] - I0[j];
            float arg = __builtin_fmaf(d * d, C1, (dz == 1) ? 0.f : LWZ1);
            float w = exp2f(arg);
            den[j] += w;
            float4 p = colP[j + dz];
            num[j].x = __builtin_fmaf(w, p.x, num[j].x);
            num[j].y = __builtin_fmaf(w, p.y, num[j].y);
            num[j].z = __builtin_fmaf(w, p.z, num[j].z);
            num[j].w = __builtin_fmaf(w, p.w, num[j].w);
          }
        }
      }
    }
  }

  float pn[16], pd[16];
#pragma unroll
  for (int i = 0; i < 16; ++i) { pn[i] = 0.f; pd[i] = 0.f; }
#pragma unroll
  for (int b = 0; b < 4; ++b) {
#pragma unroll
    for (int j = 0; j < ZLEN; ++j) {
      const float* pp = preds + b * 4 * P3 + ((x * Pdim + y) * Pdim + z0 + j);
      float nsv[4] = {num[j].x, num[j].y, num[j].z, num[j].w};
#pragma unroll
      for (int k = 0; k < 4; ++k) {
        float pv = pp[k * P3];
        pn[b * 4 + k] = __builtin_fmaf(pv, nsv[k], pn[b * 4 + k]);
        pd[b * 4 + k] = __builtin_fmaf(pv, den[j], pd[b * 4 + k]);
      }
    }
  }
#pragma unroll
  for (int i = 0; i < 16; ++i) {
#pragma unroll
    for (int off = 32; off > 0; off >>= 1) {
      pn[i] += __shfl_down(pn[i], off, 64);
      pd[i] += __shfl_down(pd[i], off, 64);
    }
  }
  const int wave = t >> 6, lane = t & 63;
  if (lane == 0) {
#pragma unroll
    for (int i = 0; i < 16; ++i) { red[wave][i] = pn[i]; red[wave][16 + i] = pd[i]; }
  }
  __syncthreads();
  if (t < 32) {
    float s = red[0][t] + red[1][t] + red[2][t] + red[3][t];
    int bid = blockIdx.x + 8 * (blockIdx.y + 8 * (int)blockIdx.z);
    atomicAdd(&acc[(bid & (NREP - 1)) * 32 + t], s);
  }
}

__global__ void ncuts_zero(float* __restrict__ acc) {
  int t = threadIdx.x;
  if (t < NREP * 32) acc[t] = 0.f;
}

// ===========================================================================
extern "C" void kernel_launch(void* const* d_in, const int* in_sizes, int n_in,
                              void* d_out, int out_size, void* d_ws, size_t ws_size,
                              hipStream_t stream) {
  const float* batch = (const float*)d_in[0];
  const float* preds = (const float*)d_in[1];
  float* out = (float*)d_out;

  const size_t ubytes = (size_t)40 * P3 * 4;            // 40 MB of box fields
  const size_t need   = ubytes + 4096;
  if (ws_size >= need) {
    float* U   = (float*)((char*)d_ws + 256);           // guard word before/after
    float* acc = (float*)((char*)d_ws + ubytes + 1024); // NREP*32 floats
    hipLaunchKernelGGL(ncuts_passx, dim3(16, 20, 2), dim3(256), 0, stream,
                       batch, preds, U, acc);
    hipLaunchKernelGGL(ncuts_passy, dim3(16, 40), dim3(256), 0, stream, U);
    hipLaunchKernelGGL(ncuts_contract, dim3(512), dim3(256), 0, stream,
                       batch, preds, U, acc);
    hipLaunchKernelGGL(ncuts_final, dim3(1), dim3(64), 0, stream, acc, out);
  } else {
    float* acc = (float*)d_ws;
    hipLaunchKernelGGL(ncuts_zero, dim3(1), dim3(512), 0, stream, acc);
    hipLaunchKernelGGL(ncuts_main, dim3(8, 8, 8), dim3(256), 0, stream,
                       batch, preds, acc);
    hipLaunchKernelGGL(ncuts_final, dim3(1), dim3(64), 0, stream, acc, out);
  }
}

// Round 3
// 97.079 us; speedup vs baseline: 1.8779x; 1.1498x over previous
//
#include <hip/hip_runtime.h>
#include <hip/hip_fp16.h>

// SoftNCutsLoss via rank-2 separable factorization of the bilateral weight.
// w = exp(-(Iw-I0)^2/100)*wz(dz) ; exp(Iw*I0/50) ~= 1 + Iw*I0/50 (rel err <= 2e-4)
//  => w ~= [g(I0)]*[g(Iw)]*wz + [g(I0)*I0/50]*[g(Iw)*Iw]*wz,  g(u)=exp(-u^2/100)
// Pipeline:
//   passx  : u_m = g*I^m*p, 9-wide running box along x, pack (m0,m1) as half2
//   passyz : 9-wide running box along y, then 3-tap z-comb via lane shuffles
//            (z == lane axis, volume edge == wave edge), write half2 V
//   contract: elementwise rank-2 recombine + EPS-pad den correction + fused
//            einsums + block reduce + replicated atomics
//   final  : 4 - sum_k (num+eps)/(den+eps)

constexpr int Pdim = 64;
constexpr int P3   = Pdim * Pdim * Pdim;   // 262144
constexpr int NREP = 16;

#define EPSF 2.2204460492503131e-16f

constexpr float WZ1   = 0.8290291181804004f;     // exp(-3/16)
constexpr float K2F   = 0.014426950408889634f;   // log2(e)/100
constexpr float C1F   = 0.02f;                   // 1/50
constexpr float WFULL = 81.0f * (1.0f + 2.0f * WZ1);

// ---------------------------------------------------------------------------
// Pass X: half2(U0,U1) = BoxX(g*p, g*I*p). thread = x-line at fixed (y,z).
// ---------------------------------------------------------------------------
template<int X0, int NX, int FIRSTW>
__device__ __forceinline__ void passx_body(const float* __restrict__ Ip,
                                           const float* __restrict__ Pp,
                                           __half2* __restrict__ Uo,
                                           bool isden) {
  float w0[9], w1[9];
#pragma unroll
  for (int i = 0; i < 9; ++i) { w0[i] = 0.f; w1[i] = 0.f; }
  float s0 = 0.f, s1 = 0.f;
#pragma unroll
  for (int i = 0; i < NX; ++i) {
    const int x = X0 + i;
    float u0 = 0.f, u1 = 0.f;
    if (x < 64) {                       // zero-pad outside (pred pad ~ EPS ~ 0)
      float I = Ip[x << 12];
      float g = exp2f(-I * I * K2F);
      float p = isden ? 1.f : Pp[x << 12];
      u0 = g * p;
      u1 = u0 * I;
    }
    const int r = i % 9;                // static after full unroll
    s0 += u0 - w0[r]; w0[r] = u0;
    s1 += u1 - w1[r]; w1[r] = u1;
    if (i >= FIRSTW) Uo[(x - 4) << 12] = __floats2half2_rn(s0, s1);
  }
}

__global__ __launch_bounds__(256)
void ncuts_passx(const float* __restrict__ batch, const float* __restrict__ preds,
                 __half2* __restrict__ U, float* __restrict__ acc) {
  const int t = threadIdx.x;
  if (blockIdx.x == 0 && blockIdx.y == 0 && blockIdx.z == 0) {
    acc[t] = 0.f; acc[t + 256] = 0.f;   // zero NREP*32 = 512 accumulators
  }
  const int z = t & 63, ys = t >> 6;
  const int y = blockIdx.x * 4 + ys;
  const int pair = blockIdx.y;          // b*5 + c, c=0..3 pred channel, c=4 den
  const int b = pair / 5, c = pair - 5 * b;
  const bool isden = (c == 4);
  const int lin = (y << 6) + z;
  const float* Ip = batch + b * P3 + lin;
  const float* Pp = isden ? Ip : preds + (b * 4 + c) * P3 + lin;
  __half2* Uo = U + pair * P3 + lin;
  if (blockIdx.z == 0) passx_body< 0, 36, 4>(Ip, Pp, Uo, isden);  // out x 0..31
  else                 passx_body<28, 40, 8>(Ip, Pp, Uo, isden);  // out x 32..63
}

// ---------------------------------------------------------------------------
// Pass YZ: 9-wide box along y (registers), 3-tap z-comb via shuffles (z=lane).
// ---------------------------------------------------------------------------
template<int Y0, int NY, int FIRSTW>
__device__ __forceinline__ void passyz_body(const __half2* __restrict__ src,
                                            __half2* __restrict__ dst, int z) {
  float w0[9], w1[9];
#pragma unroll
  for (int i = 0; i < 9; ++i) { w0[i] = 0.f; w1[i] = 0.f; }
  float s0 = 0.f, s1 = 0.f;
#pragma unroll
  for (int i = 0; i < NY; ++i) {
    const int y = Y0 + i;
    float u0 = 0.f, u1 = 0.f;
    if (y < 64) {
      float2 u = __half22float2(src[y << 6]);
      u0 = u.x; u1 = u.y;
    }
    const int r = i % 9;
    s0 += u0 - w0[r]; w0[r] = u0;
    s1 += u1 - w1[r]; w1[r] = u1;
    if (i >= FIRSTW) {
      float up0 = __shfl_up(s0, 1, 64),   up1 = __shfl_up(s1, 1, 64);
      float dn0 = __shfl_down(s0, 1, 64), dn1 = __shfl_down(s1, 1, 64);
      if (z == 0)  { up0 = 0.f; up1 = 0.f; }   // z-boundary == wave boundary
      if (z == 63) { dn0 = 0.f; dn1 = 0.f; }
      float v0 = __builtin_fmaf(WZ1, up0 + dn0, s0);
      float v1 = __builtin_fmaf(WZ1, up1 + dn1, s1);
      dst[(y - 4) << 6] = __floats2half2_rn(v0, v1);
    }
  }
}

__global__ __launch_bounds__(256)
void ncuts_passyz(const __half2* __restrict__ U, __half2* __restrict__ V) {
  const int t = threadIdx.x;
  const int z = t & 63, xs = t >> 6;
  const int x = blockIdx.x * 4 + xs;
  const int pair = blockIdx.y;
  const __half2* src = U + pair * P3 + (x << 12) + z;
  __half2* dst = V + pair * P3 + (x << 12) + z;
  if (blockIdx.z == 0) passyz_body< 0, 36, 4>(src, dst, z);  // out y 0..31
  else                 passyz_body<28, 40, 8>(src, dst, z);  // out y 32..63
}

// ---------------------------------------------------------------------------
// Contract: rank-2 recombine, den boundary fix, fused einsums, block reduce.
// ---------------------------------------------------------------------------
__global__ __launch_bounds__(256)
void ncuts_contract(const float* __restrict__ batch, const float* __restrict__ preds,
                    const __half2* __restrict__ V, float* __restrict__ acc) {
  __shared__ float red[4][32];
  const int t = threadIdx.x;
  float pn[16], pd[16];
#pragma unroll
  for (int i = 0; i < 16; ++i) { pn[i] = 0.f; pd[i] = 0.f; }

#pragma unroll 1
  for (int it = 0; it < 2; ++it) {
    const int v = blockIdx.x * 512 + it * 256 + t;
    const int z = v & 63, y = (v >> 6) & 63, x = v >> 12;

    float a0[4], a1[4], gsum = 0.f;
#pragma unroll
    for (int b = 0; b < 4; ++b) {
      float I = batch[b * P3 + v];
      float g = exp2f(-I * I * K2F);
      a0[b] = g; a1[b] = g * I * C1F; gsum += g;
    }

    float ns[4] = {0.f, 0.f, 0.f, 0.f};
    float ds = 0.f;
#pragma unroll
    for (int b = 0; b < 4; ++b) {
#pragma unroll
      for (int c = 0; c < 5; ++c) {
        float2 u = __half22float2(V[(b * 5 + c) * P3 + v]);
        float zc = __builtin_fmaf(a0[b], u.x, a1[b] * u.y);
        if (c < 4) ns[c] += zc;
        else       ds    += zc;
      }
    }
    // den boundary correction: out-of-bounds image cells have w ~= g(I0)*wz(dz)
    float cx = (float)(9 - max(0, 4 - x) - max(0, x - 59));
    float cy = (float)(9 - max(0, 4 - y) - max(0, y - 59));
    float cz = 1.f + WZ1 * (float)((int)(z > 0) + (int)(z < 63));
    ds = __builtin_fmaf(gsum, WFULL - cx * cy * cz, ds);

#pragma unroll
    for (int b = 0; b < 4; ++b) {
#pragma unroll
      for (int k = 0; k < 4; ++k) {
        float p = preds[(b * 4 + k) * P3 + v];
        pn[b * 4 + k] = __builtin_fmaf(p, ns[k], pn[b * 4 + k]);
        pd[b * 4 + k] = __builtin_fmaf(p, ds,    pd[b * 4 + k]);
      }
    }
  }

#pragma unroll
  for (int i = 0; i < 16; ++i) {
#pragma unroll
    for (int off = 32; off > 0; off >>= 1) {
      pn[i] += __shfl_down(pn[i], off, 64);
      pd[i] += __shfl_down(pd[i], off, 64);
    }
  }
  const int wave = t >> 6, lane = t & 63;
  if (lane == 0) {
#pragma unroll
    for (int i = 0; i < 16; ++i) { red[wave][i] = pn[i]; red[wave][16 + i] = pd[i]; }
  }
  __syncthreads();
  if (t < 32) {
    float s = red[0][t] + red[1][t] + red[2][t] + red[3][t];
    atomicAdd(&acc[(blockIdx.x & (NREP - 1)) * 32 + t], s);
  }
}

__global__ void ncuts_final(const float* __restrict__ acc, float* __restrict__ out) {
  __shared__ float loss[16];
  int t = threadIdx.x;
  if (t < 16) {
    float n = 0.f, d = 0.f;
    for (int r = 0; r < NREP; ++r) { n += acc[r * 32 + t]; d += acc[r * 32 + 16 + t]; }
    loss[t] = (n + EPSF) / (d + EPSF);
  }
  __syncthreads();
  if (t < 4) {
    float s = loss[t * 4] + loss[t * 4 + 1] + loss[t * 4 + 2] + loss[t * 4 + 3];
    out[t] = 4.0f - s;
  }
}

// ===========================================================================
// Fallback (round-1 direct kernel) if the workspace is too small.
// ===========================================================================
constexpr int Rxy = 4;
constexpr int TX = 8, TY = 8;
constexpr int ZLEN = 2;
constexpr int RGX = 16, RGY = 16, RGZ = 10;
constexpr int YP = 17, ZP = 11;

__global__ __launch_bounds__(256, 2)
void ncuts_main(const float* __restrict__ batch, const float* __restrict__ preds,
                float* __restrict__ acc) {
  __shared__ float  sB[RGX][YP][ZP];
  __shared__ float4 sP[RGX][YP][ZP];
  __shared__ float  red[4][32];

  const int t = threadIdx.x;
  const int tx = t & 7, ty = (t >> 3) & 7, tzt = t >> 6;
  const int bx0 = blockIdx.x * TX, by0 = blockIdx.y * TY, bz0 = blockIdx.z * 8;
  const int x = bx0 + tx, y = by0 + ty, z0 = bz0 + tzt * ZLEN;
  const int zc = tzt * ZLEN;

  float  den[ZLEN];
  float4 num[ZLEN];
#pragma unroll
  for (int j = 0; j < ZLEN; ++j) { den[j] = 0.f; num[j] = make_float4(0.f, 0.f, 0.f, 0.f); }

  const float C1 = -0.014426950408889634f;
  const float LWZ1 = -0.27050531991668065f;

  for (int b = 0; b < 4; ++b) {
    __syncthreads();
    for (int idx = t; idx < RGX * RGY * RGZ; idx += 256) {
      int rz = idx % RGZ, rq = idx / RGZ, ry = rq % RGY, rx = rq / RGY;
      int gx = bx0 + rx - Rxy, gy = by0 + ry - Rxy, gz = bz0 + rz - 1;
      bool in = ((unsigned)gx < 64u) & ((unsigned)gy < 64u) & ((unsigned)gz < 64u);
      float v = EPSF; float4 pv = make_float4(EPSF, EPSF, EPSF, EPSF);
      if (in) {
        int gi = (gx * Pdim + gy) * Pdim + gz;
        v = batch[b * P3 + gi];
        const float* pp = preds + b * 4 * P3 + gi;
        pv.x = pp[0]; pv.y = pp[P3]; pv.z = pp[2 * P3]; pv.w = pp[3 * P3];
      }
      sB[rx][ry][rz] = v; sP[rx][ry][rz] = pv;
    }
    __syncthreads();

    float I0[ZLEN];
#pragma unroll
    for (int j = 0; j < ZLEN; ++j) I0[j] = sB[tx + Rxy][ty + Rxy][zc + 1 + j];

#pragma unroll 1
    for (int dy = 0; dy < 9; ++dy) {
#pragma unroll 3
      for (int dx = 0; dx < 9; ++dx) {
        const float*  cb = &sB[tx + dx][ty + dy][zc];
        const float4* cp = &sP[tx + dx][ty + dy][zc];
        float colB[ZLEN + 2]; float4 colP[ZLEN + 2];
#pragma unroll
        for (int j = 0; j < ZLEN + 2; ++j) { colB[j] = cb[j]; colP[j] = cp[j]; }
#pragma unroll
        for (int j = 0; j < ZLEN; ++j) {
#pragma unroll
          for (int dz = 0; dz < 3; ++dz) {
            float d = colB[j + dz] - I0[j];
            float arg = __builtin_fmaf(d * d, C1, (dz == 1) ? 0.f : LWZ1);
            float w = exp2f(arg);
            den[j] += w;
            float4 p = colP[j + dz];
            num[j].x = __builtin_fmaf(w, p.x, num[j].x);
            num[j].y = __builtin_fmaf(w, p.y, num[j].y);
            num[j].z = __builtin_fmaf(w, p.z, num[j].z);
            num[j].w = __builtin_fmaf(w, p.w, num[j].w);
          }
        }
      }
    }
  }

  float pn[16], pd[16];
#pragma unroll
  for (int i = 0; i < 16; ++i) { pn[i] = 0.f; pd[i] = 0.f; }
#pragma unroll
  for (int b = 0; b < 4; ++b) {
#pragma unroll
    for (int j = 0; j < ZLEN; ++j) {
      const float* pp = preds + b * 4 * P3 + ((x * Pdim + y) * Pdim + z0 + j);
      float nsv[4] = {num[j].x, num[j].y, num[j].z, num[j].w};
#pragma unroll
      for (int k = 0; k < 4; ++k) {
        float pv = pp[k * P3];
        pn[b * 4 + k] = __builtin_fmaf(pv, nsv[k], pn[b * 4 + k]);
        pd[b * 4 + k] = __builtin_fmaf(pv, den[j], pd[b * 4 + k]);
      }
    }
  }
#pragma unroll
  for (int i = 0; i < 16; ++i) {
#pragma unroll
    for (int off = 32; off > 0; off >>= 1) {
      pn[i] += __shfl_down(pn[i], off, 64);
      pd[i] += __shfl_down(pd[i], off, 64);
    }
  }
  const int wave = t >> 6, lane = t & 63;
  if (lane == 0) {
#pragma unroll
    for (int i = 0; i < 16; ++i) { red[wave][i] = pn[i]; red[wave][16 + i] = pd[i]; }
  }
  __syncthreads();
  if (t < 32) {
    float s = red[0][t] + red[1][t] + red[2][t] + red[3][t];
    int bid = blockIdx.x + 8 * (blockIdx.y + 8 * (int)blockIdx.z);
    atomicAdd(&acc[(bid & (NREP - 1)) * 32 + t], s);
  }
}

__global__ void ncuts_zero(float* __restrict__ acc) {
  int t = threadIdx.x;
  if (t < NREP * 32) acc[t] = 0.f;
}

// ===========================================================================
extern "C" void kernel_launch(void* const* d_in, const int* in_sizes, int n_in,
                              void* d_out, int out_size, void* d_ws, size_t ws_size,
                              hipStream_t stream) {
  const float* batch = (const float*)d_in[0];
  const float* preds = (const float*)d_in[1];
  float* out = (float*)d_out;

  const size_t fbytes = (size_t)20 * P3 * sizeof(__half2);   // 20 MB per stage
  const size_t need   = 2 * fbytes + 8192;
  if (ws_size >= need) {
    __half2* U   = (__half2*)((char*)d_ws + 256);
    __half2* V   = (__half2*)((char*)d_ws + 256 + fbytes);
    float*   acc = (float*)((char*)d_ws + 512 + 2 * fbytes); // NREP*32 floats
    hipLaunchKernelGGL(ncuts_passx,  dim3(16, 20, 2), dim3(256), 0, stream,
                       batch, preds, U, acc);
    hipLaunchKernelGGL(ncuts_passyz, dim3(16, 20, 2), dim3(256), 0, stream, U, V);
    hipLaunchKernelGGL(ncuts_contract, dim3(512), dim3(256), 0, stream,
                       batch, preds, V, acc);
    hipLaunchKernelGGL(ncuts_final, dim3(1), dim3(64), 0, stream, acc, out);
  } else {
    float* acc = (float*)d_ws;
    hipLaunchKernelGGL(ncuts_zero, dim3(1), dim3(512), 0, stream, acc);
    hipLaunchKernelGGL(ncuts_main, dim3(8, 8, 8), dim3(256), 0, stream,
                       batch, preds, acc);
    hipLaunchKernelGGL(ncuts_final, dim3(1), dim3(64), 0, stream, acc, out);
  }
}